// Round 14
// baseline (151.251 us; speedup 1.0000x reference)
//
#include <hip/hip_runtime.h>

#define NMN 100000
#define NPV 20000
#define DMF 128
#define DPF 64
#define NE  500000
#define HID 128
#define LAT 32
#define NACT (2*NPV)                  // 40000 edge-active nodes
#define OUT_PROV (NMN*DMF)            // 12,800,000
#define OUT_LOG  (OUT_PROV + NPV*DPF) // 14,080,000
#define CAP 128                       // CSR bucket capacity per dst (max deg ~60)

typedef __attribute__((ext_vector_type(8))) short bf16x8;   // 8 bf16 = 4 VGPR
typedef __attribute__((ext_vector_type(4))) float f32x4;    // MFMA C/D

__device__ __forceinline__ ushort f2bf(float f) {
  unsigned u = __float_as_uint(f);
  u = (u + 0x7fffu + ((u >> 16) & 1u)) >> 16;   // RNE
  return (ushort)u;
}
__device__ __forceinline__ float bf2f(ushort h) {
  return __uint_as_float(((unsigned)h) << 16);
}
__device__ __forceinline__ unsigned pack2(float a, float b) {
  return (unsigned)f2bf(a) | ((unsigned)f2bf(b) << 16);
}
__device__ __forceinline__ float lo16(unsigned u) { return bf2f((ushort)(u & 0xffffu)); }
__device__ __forceinline__ float hi16(unsigned u) { return bf2f((ushort)(u >> 16)); }

// ---------------- merged prep: fill CSR + zero logits (blocks 0..1953), transposes (1954..2049) ----------------
__global__ __launch_bounds__(256) void k_prepfill(const int* __restrict__ pidx,
                                                  const int* __restrict__ midx,
                                                  int* __restrict__ cursor,
                                                  int* __restrict__ csr,
                                                  const float* __restrict__ W1,
                                                  const float* __restrict__ W2,
                                                  const float* __restrict__ Wd,
                                                  ushort* __restrict__ W1t,
                                                  ushort* __restrict__ W2t,
                                                  ushort* __restrict__ Wdt,
                                                  float* __restrict__ out) {
  int tid = threadIdx.x;
  if (blockIdx.x < 1954) {
    int e = blockIdx.x*256 + tid;
    if (e >= NE) return;
    out[OUT_LOG + e] = 0.f;
    int p = pidx[e], m = midx[e];
    int sa = NPV + (m < NPV ? m : NPV - 1);      // clamped provider-side src
    int pos = atomicAdd(&cursor[p], 1);
    if (pos < CAP) csr[p*CAP + pos] = sa;        // edge into member node p
    if (m < NPV) {
      int da = NPV + m;
      int pos2 = atomicAdd(&cursor[da], 1);
      if (pos2 < CAP) csr[da*CAP + pos2] = p;    // edge into provider node da
    }
    return;
  }
  int i = (blockIdx.x - 1954)*256 + tid;
  if (i < 16384) {                       // W1t[n*128+k] = W1[k][n]
    int n = i >> 7, k = i & 127;
    W1t[i] = f2bf(W1[k*HID + n]);
  } else if (i < 20480) {                // W2t[n*128+k] = W2[k][n]
    int j = i - 16384;
    int n = j >> 7, k = j & 127;
    W2t[j] = f2bf(W2[k*LAT + n]);
  } else if (i < 24576) {                // Wdt[n*32+k] = Wd[k][n]
    int j = i - 20480;
    int n = j >> 5, k = j & 31;
    Wdt[j] = f2bf(Wd[k*DMF + n]);
  }
}

// ---------------- xw1 = x_active @ W1, MFMA, 64 rows/block; COLUMN-TILED store + dinv ----------------
__global__ __launch_bounds__(256) void k_xw1m(const float* __restrict__ xm,
                                              const float* __restrict__ xp,
                                              const ushort* __restrict__ W1t,
                                              const int* __restrict__ cursor,
                                              float* __restrict__ dinv,
                                              ushort* __restrict__ xw1t) {   // [4][NACT][32]
  __shared__ __align__(16) ushort As[64*136];
  __shared__ __align__(16) ushort Bs[128*136];
  int tid = threadIdx.x;
  int gi = blockIdx.x*256 + tid;
  if (gi < NACT) dinv[gi] = rsqrtf((float)(cursor[gi] + 1));  // deg = edges + self
  int rbase = blockIdx.x * 64;
  for (int i = tid; i < 2048; i += 256) {
    int n = i >> 4, c = (i & 15) * 8;
    *(uint4*)&Bs[n*136 + c] = *(const uint4*)&W1t[n*128 + c];
  }
  for (int i = tid; i < 1024; i += 256) {
    int r = i >> 4, c = (i & 15) * 8;
    int a = rbase + r;
    float4 v0 = make_float4(0,0,0,0), v1 = v0;
    if (a < NPV) {
      v0 = *(const float4*)&xm[(size_t)a*DMF + c];
      v1 = *(const float4*)&xm[(size_t)a*DMF + c + 4];
    } else if (c < DPF) {
      int p = a - NPV;
      v0 = *(const float4*)&xp[(size_t)p*DPF + c];
      v1 = *(const float4*)&xp[(size_t)p*DPF + c + 4];
    }
    uint4 u;
    u.x = pack2(v0.x, v0.y); u.y = pack2(v0.z, v0.w);
    u.z = pack2(v1.x, v1.y); u.w = pack2(v1.z, v1.w);
    *(uint4*)&As[r*136 + c] = u;
  }
  __syncthreads();
  int w = tid >> 6, l = tid & 63;
  int mrow = w*16, cl = l & 15, jg = l >> 4;
  bf16x8 af[4];
  #pragma unroll
  for (int s = 0; s < 4; ++s)
    af[s] = *(const bf16x8*)&As[(mrow + cl)*136 + s*32 + jg*8];
  #pragma unroll
  for (int nt = 0; nt < 8; ++nt) {
    f32x4 acc = {0.f,0.f,0.f,0.f};
    #pragma unroll
    for (int s = 0; s < 4; ++s) {
      bf16x8 bf = *(const bf16x8*)&Bs[(nt*16 + cl)*136 + s*32 + jg*8];
      acc = __builtin_amdgcn_mfma_f32_16x16x32_bf16(af[s], bf, acc, 0, 0, 0);
    }
    int col = nt*16 + cl;
    int t = col >> 5, ct = col & 31;               // column tile, col-in-tile
    #pragma unroll
    for (int i = 0; i < 4; ++i) {
      int grow = rbase + mrow + jg*4 + i;
      xw1t[((size_t)t*NACT + grow)*32 + ct] = f2bf(acc[i]);
    }
  }
}

// ---------------- gather1 column-tiled: 4 passes x 5000 blocks; balanced pair/wave ----------------
__global__ __launch_bounds__(256) void k_g1t(const int* __restrict__ cursor,
                                             const int* __restrict__ csr,
                                             const float* __restrict__ dinv,
                                             const ushort* __restrict__ xw1t,  // [4][NACT][32]
                                             const float* __restrict__ b1,
                                             ushort* __restrict__ ht) {        // [4][NACT][32]
  int tid = threadIdx.x;
  int t = blockIdx.x / 5000;             // column tile (dispatch-ordered phases)
  int b = blockIdx.x % 5000;
  int wv = tid >> 6, l = tid & 63;
  int wid = b*4 + wv;                    // 20000 wave-ids
  int dA = wid;                          // member dst (deg ~25)
  int dB = NPV + wid;                    // provider dst (deg ~5)
  int cntA = cursor[dA]; if (cntA > CAP) cntA = CAP;
  int cntB = cursor[dB]; if (cntB > CAP) cntB = CAP;
  float ddA = dinv[dA], ddB = dinv[dB];
  int s = l >> 4;                        // edge-slot (stride-4 stream)
  int cc = l & 15;                       // u32 col in tile (bf16 cols 2cc,2cc+1)
  const unsigned* xb = (const unsigned*)xw1t + (size_t)t*NACT*16;
  float ax = 0.f, ay = 0.f, gx = 0.f, gy = 0.f;
  if (s == 0) {                          // self terms, slot-0 stream only
    unsigned u = xb[(size_t)dA*16 + cc];
    ax = ddA*lo16(u); ay = ddA*hi16(u);
    unsigned v = xb[(size_t)dB*16 + cc];
    gx = ddB*lo16(v); gy = ddB*hi16(v);
  }
  int baseA = dA*CAP, baseB = dB*CAP;
  int eA = s, eB = s;
  #pragma unroll 2
  for (; eA < cntA && eB < cntB; eA += 4, eB += 4) {   // dual: 8 rows in flight
    int iA = csr[baseA + eA], iB = csr[baseB + eB];
    float dsA = dinv[iA], dsB = dinv[iB];
    unsigned u = xb[(size_t)iA*16 + cc];
    unsigned v = xb[(size_t)iB*16 + cc];
    ax += dsA*lo16(u); ay += dsA*hi16(u);
    gx += dsB*lo16(v); gy += dsB*hi16(v);
  }
  #pragma unroll 2
  for (; eA < cntA; eA += 4) {
    int iA = csr[baseA + eA];
    float dsA = dinv[iA];
    unsigned u = xb[(size_t)iA*16 + cc];
    ax += dsA*lo16(u); ay += dsA*hi16(u);
  }
  #pragma unroll 2
  for (; eB < cntB; eB += 4) {
    int iB = csr[baseB + eB];
    float dsB = dinv[iB];
    unsigned v = xb[(size_t)iB*16 + cc];
    gx += dsB*lo16(v); gy += dsB*hi16(v);
  }
  // combine 4 slot streams (same order as r13: (s0+s1)+(s2+s3)) — bit-identical
  ax += __shfl_xor(ax,16); ay += __shfl_xor(ay,16);
  gx += __shfl_xor(gx,16); gy += __shfl_xor(gy,16);
  ax += __shfl_xor(ax,32); ay += __shfl_xor(ay,32);
  gx += __shfl_xor(gx,32); gy += __shfl_xor(gy,32);
  float2 bb = ((const float2*)b1)[t*16 + cc];
  float rAx = ddA*ax + bb.x; rAx = rAx > 0.f ? rAx : 0.f;
  float rAy = ddA*ay + bb.y; rAy = rAy > 0.f ? rAy : 0.f;
  float rBx = ddB*gx + bb.x; rBx = rBx > 0.f ? rBx : 0.f;
  float rBy = ddB*gy + bb.y; rBy = rBy > 0.f ? rBy : 0.f;
  unsigned* hb = (unsigned*)ht + (size_t)t*NACT*16;
  if (s == 0)      hb[(size_t)dA*16 + cc] = pack2(rAx, rAy);
  else if (s == 1) hb[(size_t)dB*16 + cc] = pack2(rBx, rBy);
}

// ---------------- xw2 = h @ W2, MFMA (tiled-h input), 64 rows/block ----------------
__global__ __launch_bounds__(256) void k_xw2m(const ushort* __restrict__ ht,   // [4][NACT][32]
                                              const ushort* __restrict__ W2t,  // [32][128]
                                              ushort* __restrict__ xw2) {      // [NACT][32]
  int tid = threadIdx.x;
  int rbase = blockIdx.x * 64;
  int w = tid >> 6, l = tid & 63;
  int mrow = w*16, cl = l & 15, jg = l >> 4;
  int arow = rbase + mrow + cl;
  bf16x8 af[4];
  #pragma unroll
  for (int s = 0; s < 4; ++s)
    af[s] = *(const bf16x8*)&ht[((size_t)s*NACT + arow)*32 + jg*8];   // L2-hot
  #pragma unroll
  for (int nt = 0; nt < 2; ++nt) {
    f32x4 acc = {0.f,0.f,0.f,0.f};
    #pragma unroll
    for (int s = 0; s < 4; ++s) {
      bf16x8 bf = *(const bf16x8*)&W2t[(nt*16 + cl)*128 + s*32 + jg*8];  // L1 (8KB)
      acc = __builtin_amdgcn_mfma_f32_16x16x32_bf16(af[s], bf, acc, 0, 0, 0);
    }
    int col = nt*16 + cl;
    #pragma unroll
    for (int i = 0; i < 4; ++i) {
      int grow = rbase + mrow + jg*4 + i;
      xw2[(size_t)grow*LAT + col] = f2bf(acc[i]);
    }
  }
}

// ---------------- gather2 + (z @ Wdec) fused -> out; 4-slot u32 rows ----------------
__global__ __launch_bounds__(256) void k_g2f(const int* __restrict__ cursor,
                                             const int* __restrict__ csr,
                                             const float* __restrict__ dinv,
                                             const ushort* __restrict__ xw2,
                                             const float* __restrict__ b2,
                                             const ushort* __restrict__ Wdt,
                                             const float* __restrict__ bd,
                                             float* __restrict__ out) {
  __shared__ float zs[4][2][32];
  int tid = threadIdx.x;
  int wv = tid >> 6, l = tid & 63;
  int wid = blockIdx.x*4 + wv;
  int dA = wid;                          // member dst
  int dB = NPV + wid;                    // provider dst
  int cntA = cursor[dA]; if (cntA > CAP) cntA = CAP;
  int cntB = cursor[dB]; if (cntB > CAP) cntB = CAP;
  float ddA = dinv[dA], ddB = dinv[dB];
  int s = l >> 4;                        // slot (stride-4 edge stream)
  int cc = l & 15;                       // u32 col: bf16 cols 2cc, 2cc+1
  const unsigned* xb = (const unsigned*)xw2;
  float ax = 0.f, ay = 0.f, gx = 0.f, gy = 0.f;
  if (s == 0) {
    unsigned u = xb[(size_t)dA*16 + cc];
    ax = ddA*lo16(u); ay = ddA*hi16(u);
    unsigned v = xb[(size_t)dB*16 + cc];
    gx = ddB*lo16(v); gy = ddB*hi16(v);
  }
  int baseA = dA*CAP, baseB = dB*CAP;
  int eA = s, eB = s;
  #pragma unroll 2
  for (; eA < cntA && eB < cntB; eA += 4, eB += 4) {
    int iA = csr[baseA + eA], iB = csr[baseB + eB];
    float dsA = dinv[iA], dsB = dinv[iB];
    unsigned u = xb[(size_t)iA*16 + cc];
    unsigned v = xb[(size_t)iB*16 + cc];
    ax += dsA*lo16(u); ay += dsA*hi16(u);
    gx += dsB*lo16(v); gy += dsB*hi16(v);
  }
  #pragma unroll 2
  for (; eA < cntA; eA += 4) {
    int iA = csr[baseA + eA];
    float dsA = dinv[iA];
    unsigned u = xb[(size_t)iA*16 + cc];
    ax += dsA*lo16(u); ay += dsA*hi16(u);
  }
  #pragma unroll 2
  for (; eB < cntB; eB += 4) {
    int iB = csr[baseB + eB];
    float dsB = dinv[iB];
    unsigned v = xb[(size_t)iB*16 + cc];
    gx += dsB*lo16(v); gy += dsB*hi16(v);
  }
  ax += __shfl_xor(ax,16); ay += __shfl_xor(ay,16);
  gx += __shfl_xor(gx,16); gy += __shfl_xor(gy,16);
  ax += __shfl_xor(ax,32); ay += __shfl_xor(ay,32);
  gx += __shfl_xor(gx,32); gy += __shfl_xor(gy,32);
  float2 bb = ((const float2*)b2)[cc];
  float rAx = ddA*ax + bb.x, rAy = ddA*ay + bb.y;
  float rBx = ddB*gx + bb.x, rBy = ddB*gy + bb.y;
  if (s == 0) {                          // z quantized to bf16 (matches prior pipeline)
    zs[wv][0][2*cc]   = bf2f(f2bf(rAx));
    zs[wv][0][2*cc+1] = bf2f(f2bf(rAy));
  } else if (s == 1) {
    zs[wv][1][2*cc]   = bf2f(f2bf(rBx));
    zs[wv][1][2*cc+1] = bf2f(f2bf(rBy));
  }
  // fused decode: member dA -> 128 cols (c0,c1); provider dB -> 64 cols (c0)
  int c0 = l, c1 = l + 64;
  const unsigned* wd32 = (const unsigned*)Wdt;   // [n][16] u32 (k-pairs)
  float oA0 = 0.f, oA1 = 0.f, oB0 = 0.f;
  #pragma unroll 8
  for (int kk = 0; kk < 16; ++kk) {
    float za0 = zs[wv][0][2*kk], za1 = zs[wv][0][2*kk+1];
    float zb0 = zs[wv][1][2*kk], zb1 = zs[wv][1][2*kk+1];
    unsigned u0 = wd32[c0*16 + kk];
    unsigned u1 = wd32[c1*16 + kk];
    float w00 = lo16(u0), w01 = hi16(u0);
    float w10 = lo16(u1), w11 = hi16(u1);
    oA0 += za0*w00; oA0 += za1*w01;
    oA1 += za0*w10; oA1 += za1*w11;
    oB0 += zb0*w00; oB0 += zb1*w01;
  }
  out[(size_t)dA*DMF + c0] = oA0 + bd[c0];
  out[(size_t)dA*DMF + c1] = oA1 + bd[c1];
  out[OUT_PROV + (size_t)(dB-NPV)*DPF + c0] = oB0 + bd[c0];   // c0 in [0,64)
}

// ---------------- fused passive MLP, MFMA, 64 rows/block ----------------
__global__ __launch_bounds__(256) void k_passm(const float* __restrict__ xm,
                                               const ushort* __restrict__ W1t,
                                               const float* __restrict__ b1,
                                               const ushort* __restrict__ W2t,
                                               const float* __restrict__ b2,
                                               const ushort* __restrict__ Wdt,
                                               const float* __restrict__ bd,
                                               float* __restrict__ out) {
  __shared__ __align__(16) ushort XH[64*136];   // x, overwritten by h (wave-private rows)
  __shared__ __align__(16) ushort ZB[64*40];
  __shared__ __align__(16) ushort B1s[128*136];
  __shared__ __align__(16) ushort B2s[32*136];
  __shared__ __align__(16) ushort Bds[128*40];
  int tid = threadIdx.x;
  int rbase = NPV + blockIdx.x * 64;            // member rows 20000..99999
  for (int i = tid; i < 2048; i += 256) {
    int n = i >> 4, c = (i & 15) * 8;
    *(uint4*)&B1s[n*136 + c] = *(const uint4*)&W1t[n*128 + c];
  }
  for (int i = tid; i < 512; i += 256) {
    int n = i >> 4, c = (i & 15) * 8;
    *(uint4*)&B2s[n*136 + c] = *(const uint4*)&W2t[n*128 + c];
  }
  for (int i = tid; i < 512; i += 256) {
    int n = i >> 2, c = (i & 3) * 8;
    *(uint4*)&Bds[n*40 + c] = *(const uint4*)&Wdt[n*32 + c];
  }
  for (int i = tid; i < 1024; i += 256) {
    int r = i >> 4, c = (i & 15) * 8;
    float4 v0 = *(const float4*)&xm[(size_t)(rbase + r)*DMF + c];
    float4 v1 = *(const float4*)&xm[(size_t)(rbase + r)*DMF + c + 4];
    uint4 u;
    u.x = pack2(v0.x, v0.y); u.y = pack2(v0.z, v0.w);
    u.z = pack2(v1.x, v1.y); u.w = pack2(v1.z, v1.w);
    *(uint4*)&XH[r*136 + c] = u;
  }
  __syncthreads();                              // the ONLY barrier
  int w = tid >> 6, l = tid & 63;
  int mrow = w*16, cl = l & 15, jg = l >> 4;
  // phase 1: h = relu(x@W1 + b1) -> XH in place (rows wave-private; A preloaded)
  {
    bf16x8 af[4];
    #pragma unroll
    for (int s = 0; s < 4; ++s)
      af[s] = *(const bf16x8*)&XH[(mrow + cl)*136 + s*32 + jg*8];
    #pragma unroll
    for (int nt = 0; nt < 8; ++nt) {
      f32x4 acc = {0.f,0.f,0.f,0.f};
      #pragma unroll
      for (int s = 0; s < 4; ++s) {
        bf16x8 bf = *(const bf16x8*)&B1s[(nt*16 + cl)*136 + s*32 + jg*8];
        acc = __builtin_amdgcn_mfma_f32_16x16x32_bf16(af[s], bf, acc, 0, 0, 0);
      }
      int col = nt*16 + cl;
      float bv = b1[col];
      #pragma unroll
      for (int i = 0; i < 4; ++i) {
        float v = acc[i] + bv;
        v = v > 0.f ? v : 0.f;
        XH[(mrow + jg*4 + i)*136 + col] = f2bf(v);
      }
    }
  }
  // phase 2: z = h@W2 + b2 -> ZB
  {
    bf16x8 af[4];
    #pragma unroll
    for (int s = 0; s < 4; ++s)
      af[s] = *(const bf16x8*)&XH[(mrow + cl)*136 + s*32 + jg*8];
    #pragma unroll
    for (int nt = 0; nt < 2; ++nt) {
      f32x4 acc = {0.f,0.f,0.f,0.f};
      #pragma unroll
      for (int s = 0; s < 4; ++s) {
        bf16x8 bf = *(const bf16x8*)&B2s[(nt*16 + cl)*136 + s*32 + jg*8];
        acc = __builtin_amdgcn_mfma_f32_16x16x32_bf16(af[s], bf, acc, 0, 0, 0);
      }
      int col = nt*16 + cl;
      float bv = b2[col];
      #pragma unroll
      for (int i = 0; i < 4; ++i)
        ZB[(mrow + jg*4 + i)*40 + col] = f2bf(acc[i] + bv);
    }
  }
  // phase 3: xhat = z@Wd + bd -> out
  {
    bf16x8 af = *(const bf16x8*)&ZB[(mrow + cl)*40 + jg*8];
    #pragma unroll
    for (int nt = 0; nt < 8; ++nt) {
      f32x4 acc = {0.f,0.f,0.f,0.f};
      bf16x8 bf = *(const bf16x8*)&Bds[(nt*16 + cl)*40 + jg*8];
      acc = __builtin_amdgcn_mfma_f32_16x16x32_bf16(af, bf, acc, 0, 0, 0);
      int col = nt*16 + cl;
      float bv = bd[col];
      #pragma unroll
      for (int i = 0; i < 4; ++i) {
        size_t grow = rbase + mrow + jg*4 + i;
        out[grow*DMF + col] = acc[i] + bv;
      }
    }
  }
}

extern "C" void kernel_launch(void* const* d_in, const int* in_sizes, int n_in,
                              void* d_out, int out_size, void* d_ws, size_t ws_size,
                              hipStream_t stream) {
  const float* xm   = (const float*)d_in[0];
  const float* xp   = (const float*)d_in[1];
  const int*   pidx = (const int*)d_in[2];
  const int*   midx = (const int*)d_in[3];
  const float* W1   = (const float*)d_in[4];
  const float* b1   = (const float*)d_in[5];
  const float* W2   = (const float*)d_in[6];
  const float* b2   = (const float*)d_in[7];
  const float* Wd   = (const float*)d_in[8];
  const float* bd   = (const float*)d_in[9];
  float* out = (float*)d_out;

  // ws layout (bytes):
  // cursor[160000] | csr[20480000] | W1t[32768] W2t[8192] Wdt[8192]
  // | xw1t[10240000] | ht[10240000] | xw2[2560000] | dinv[160000]  => 43,889,152 B
  if (ws_size < (size_t)43889152) return;
  char* W = (char*)d_ws;
  int*    cursor = (int*)(W + 0);
  int*    csr    = (int*)(W + 160000);
  ushort* W1t    = (ushort*)(W + 20640000);
  ushort* W2t    = (ushort*)(W + 20672768);
  ushort* Wdt    = (ushort*)(W + 20680960);
  ushort* xw1t   = (ushort*)(W + 20689152);
  ushort* ht     = (ushort*)(W + 30929152);
  ushort* xw2g   = (ushort*)(W + 41169152);
  float*  dinv   = (float*)(W + 43729152);

  hipMemsetAsync(cursor, 0, 160000, stream);
  k_prepfill <<<2050,  256, 0, stream>>>(pidx, midx, cursor, csr,
                                         W1, W2, Wd, W1t, W2t, Wdt, out);
  k_xw1m     <<<625,   256, 0, stream>>>(xm, xp, W1t, cursor, dinv, xw1t);
  k_g1t      <<<20000, 256, 0, stream>>>(cursor, csr, dinv, xw1t, b1, ht);
  k_xw2m     <<<625,   256, 0, stream>>>(ht, W2t, xw2g);
  k_g2f      <<<5000,  256, 0, stream>>>(cursor, csr, dinv, xw2g, b2, Wdt, bd, out);
  k_passm    <<<1250,  256, 0, stream>>>(xm, W1t, b1, W2t, b2, Wdt, bd, out);
}